// Round 5
// baseline (248.340 us; speedup 1.0000x reference)
//
#include <hip/hip_runtime.h>
#include <hip/hip_bf16.h>
#include <math.h>

#define B_  2
#define S_  2048
#define D_  1024
#define H_  16
#define DH_ 64
#define M_  (B_ * S_)   // 4096 tokens

typedef __attribute__((ext_vector_type(8))) short bf16x8;  // 8 bf16 (4 VGPRs)
typedef __attribute__((ext_vector_type(4))) short bf16x4;  // 4 bf16 (2 VGPRs)
typedef __attribute__((ext_vector_type(4))) float f32x4;   // MFMA C/D frag

#if __has_builtin(__builtin_amdgcn_mfma_f32_16x16x16bf16_1k)
#define HAVE_MFMA16 1
#define MFMA16(a, b, c) __builtin_amdgcn_mfma_f32_16x16x16bf16_1k(a, b, c, 0, 0, 0)
#else
#define HAVE_MFMA16 0
#endif

__device__ __forceinline__ float fast_exp2(float x) {
  return __builtin_amdgcn_exp2f(x);   // v_exp_f32
}

__device__ __forceinline__ unsigned short f2bf(float f) {
  union { float f; unsigned u; } c; c.f = f;
  unsigned u = c.u;
  return (unsigned short)((u + 0x7FFFu + ((u >> 16) & 1u)) >> 16);  // RNE
}

// pack two floats -> two bf16 (round-half-up) in one dword via v_perm
__device__ __forceinline__ unsigned pkbf(float lo, float hi) {
  union { float f; unsigned u; } a, b;
  a.f = lo; b.f = hi;
  return __builtin_amdgcn_perm(b.u + 0x8000u, a.u + 0x8000u, 0x07060302u);
}

__device__ __forceinline__ float logsig(float x) {
  return fminf(x, 0.f) - log1pf(__expf(-fabsf(x)));   // stable log_sigmoid
}

// XOR-swizzled LDS index: rows of 64 shorts (8 chunks of 8); chunk ^= row&7.
// All b128/b64 accesses stay within one chunk; <=2-way bank aliasing (free).
__device__ __forceinline__ int swz(int row, int col) {
  return (row << 6) + ((((col >> 3) ^ row) & 7) << 3) + (col & 7);
}

// ---------------------------------------------------------------------------
// Kernel 0: transpose Wq/Wk (fp32 [K][N]) -> bf16 W^T [N][K]
// ---------------------------------------------------------------------------
__global__ __launch_bounds__(256) void prep_w(
    const float* __restrict__ Wq, const float* __restrict__ Wk,
    unsigned short* __restrict__ WqT, unsigned short* __restrict__ WkT)
{
  __shared__ unsigned short T[64][72];
  const int tid = threadIdx.x;
  const int k0 = blockIdx.x * 64;
  const int n0 = blockIdx.y * 64;
  const float* W = blockIdx.z ? Wk : Wq;
  unsigned short* WT = blockIdx.z ? WkT : WqT;

  const int kr = tid >> 2, nc = (tid & 3) * 16;
  #pragma unroll
  for (int i = 0; i < 4; i++) {
    const float4 v = *(const float4*)&W[(size_t)(k0 + kr) * D_ + n0 + nc + i * 4];
    T[nc + i * 4 + 0][kr] = f2bf(v.x);
    T[nc + i * 4 + 1][kr] = f2bf(v.y);
    T[nc + i * 4 + 2][kr] = f2bf(v.z);
    T[nc + i * 4 + 3][kr] = f2bf(v.w);
  }
  __syncthreads();
  const int nr = tid >> 2, kc = (tid & 3) * 16;
  const uint4 a = *(const uint4*)&T[nr][kc];
  const uint4 b = *(const uint4*)&T[nr][kc + 8];
  *(uint4*)&WT[(size_t)(n0 + nr) * D_ + k0 + kc] = a;
  *(uint4*)&WT[(size_t)(n0 + nr) * D_ + k0 + kc + 8] = b;
}

// ---------------------------------------------------------------------------
// Kernel 1: Q = hs@Wq+bq ; K2 = logsig(logsig(Q)+Q+hs@Wk+bk)
//   outputs: Qb [M][D] bf16, K2b [M][D] bf16, QT [H*64][M] bf16 (per-head Q^T)
// Tile 128m x 64n (n-block == one head), BK=64. Register-prefetch pipeline.
// Grid (mtile fastest, 32): same m-tile -> same XCD -> hs L2 reuse.
// ---------------------------------------------------------------------------
__global__ __launch_bounds__(256, 2) void proj_kernel(
    const float* __restrict__ hs,
    const unsigned short* __restrict__ WqT, const unsigned short* __restrict__ WkT,
    const float* __restrict__ bqv, const float* __restrict__ bkv,
    unsigned short* __restrict__ Qb, unsigned short* __restrict__ K2b,
    unsigned short* __restrict__ QT)
{
  __shared__ unsigned short SM[128 * 64 + 64 * 64 + 64 * 64];  // 32 KB
  unsigned short* Ash = SM;            // [128][64] swizzled
  unsigned short* Bq  = SM + 8192;     // [64][64]  swizzled
  unsigned short* Bk  = SM + 12288;    // [64][64]  swizzled

  const int tid  = threadIdx.x;
  const int w    = tid >> 6;
  const int lane = tid & 63;
  const int quad = lane >> 4;
  const int l16  = lane & 15;
  const int m0 = blockIdx.x * 128;
  const int n0 = blockIdx.y * 64;     // = head * 64

  float bqs[4], bks[4];
  #pragma unroll
  for (int nt = 0; nt < 4; nt++) {
    bqs[nt] = bqv[n0 + nt * 16 + l16];
    bks[nt] = bkv[n0 + nt * 16 + l16];
  }

  f32x4 accQ[2][4], accK[2][4];
  #pragma unroll
  for (int st = 0; st < 2; st++)
    #pragma unroll
    for (int nt = 0; nt < 4; nt++) {
      accQ[st][nt] = (f32x4){0.f, 0.f, 0.f, 0.f};
      accK[st][nt] = (f32x4){0.f, 0.f, 0.f, 0.f};
    }

  const int am = tid >> 1, acb = (tid & 1) * 4;   // A: row, first of 4 chunks
  const int bn = tid >> 2, bcb = (tid & 3) * 2;   // B: row, first of 2 chunks

  const size_t abase = (size_t)(m0 + am) * D_;
  const size_t bbase = (size_t)(n0 + bn) * D_;

  float4 preA[4][2];
  uint4 preBq[2], preBk[2];
  #pragma unroll
  for (int i = 0; i < 4; i++) {
    preA[i][0] = *(const float4*)&hs[abase + (acb + i) * 8];
    preA[i][1] = *(const float4*)&hs[abase + (acb + i) * 8 + 4];
  }
  #pragma unroll
  for (int i = 0; i < 2; i++) {
    preBq[i] = *(const uint4*)&WqT[bbase + (bcb + i) * 8];
    preBk[i] = *(const uint4*)&WkT[bbase + (bcb + i) * 8];
  }

  for (int k0 = 0; k0 < D_; k0 += 64) {
    __syncthreads();
    // convert + write A (fp32 -> bf16 pairs), write B
    #pragma unroll
    for (int i = 0; i < 4; i++) {
      uint4 u;
      u.x = pkbf(preA[i][0].x, preA[i][0].y);
      u.y = pkbf(preA[i][0].z, preA[i][0].w);
      u.z = pkbf(preA[i][1].x, preA[i][1].y);
      u.w = pkbf(preA[i][1].z, preA[i][1].w);
      *(uint4*)&Ash[swz(am, (acb + i) * 8)] = u;
    }
    #pragma unroll
    for (int i = 0; i < 2; i++) {
      *(uint4*)&Bq[swz(bn, (bcb + i) * 8)] = preBq[i];
      *(uint4*)&Bk[swz(bn, (bcb + i) * 8)] = preBk[i];
    }
    // prefetch next K-tile while this one is consumed
    if (k0 + 64 < D_) {
      const int kn = k0 + 64;
      #pragma unroll
      for (int i = 0; i < 4; i++) {
        preA[i][0] = *(const float4*)&hs[abase + kn + (acb + i) * 8];
        preA[i][1] = *(const float4*)&hs[abase + kn + (acb + i) * 8 + 4];
      }
      #pragma unroll
      for (int i = 0; i < 2; i++) {
        preBq[i] = *(const uint4*)&WqT[bbase + kn + (bcb + i) * 8];
        preBk[i] = *(const uint4*)&WkT[bbase + kn + (bcb + i) * 8];
      }
    }
    __syncthreads();

    #pragma unroll
    for (int kk = 0; kk < 2; kk++) {
      const bf16x8 af0 = *(const bf16x8*)&Ash[swz(w * 32 + l16,      kk * 32 + quad * 8)];
      const bf16x8 af1 = *(const bf16x8*)&Ash[swz(w * 32 + 16 + l16, kk * 32 + quad * 8)];
      #pragma unroll
      for (int nt = 0; nt < 4; nt++) {
        const bf16x8 bq8 = *(const bf16x8*)&Bq[swz(nt * 16 + l16, kk * 32 + quad * 8)];
        const bf16x8 bk8 = *(const bf16x8*)&Bk[swz(nt * 16 + l16, kk * 32 + quad * 8)];
        accQ[0][nt] = __builtin_amdgcn_mfma_f32_16x16x32_bf16(af0, bq8, accQ[0][nt], 0, 0, 0);
        accQ[1][nt] = __builtin_amdgcn_mfma_f32_16x16x32_bf16(af1, bq8, accQ[1][nt], 0, 0, 0);
        accK[0][nt] = __builtin_amdgcn_mfma_f32_16x16x32_bf16(af0, bk8, accK[0][nt], 0, 0, 0);
        accK[1][nt] = __builtin_amdgcn_mfma_f32_16x16x32_bf16(af1, bk8, accK[1][nt], 0, 0, 0);
      }
    }
  }

  __syncthreads();   // K-loop done; SM reusable as Qt [64 d][136 m]
  unsigned short* Qt = SM;  // 64*136 = 8704 shorts <= 16384
  #pragma unroll
  for (int st = 0; st < 2; st++) {
    #pragma unroll
    for (int nt = 0; nt < 4; nt++) {
      float qv[4];
      #pragma unroll
      for (int r = 0; r < 4; r++) {
        const float q  = accQ[st][nt][r] + bqs[nt];
        const float kr = accK[st][nt][r] + bks[nt];
        const float k2 = logsig(logsig(q) + q + kr);
        const int m = m0 + w * 32 + st * 16 + quad * 4 + r;
        K2b[(size_t)m * D_ + n0 + nt * 16 + l16] = f2bf(k2);
        Qb [(size_t)m * D_ + n0 + nt * 16 + l16] = f2bf(q);
        qv[r] = q;
      }
      const ushort4 qu = {f2bf(qv[0]), f2bf(qv[1]), f2bf(qv[2]), f2bf(qv[3])};
      *(ushort4*)&Qt[(nt * 16 + l16) * 136 + w * 32 + st * 16 + quad * 4] = qu;
    }
  }
  __syncthreads();
  {
    const int dr = tid >> 2, mc = (tid & 3) * 32;
    #pragma unroll
    for (int i = 0; i < 4; i++) {
      const uint4 v = *(const uint4*)&Qt[dr * 136 + mc + i * 8];
      *(uint4*)&QT[(size_t)(n0 + dr) * M_ + m0 + mc + i * 8] = v;
    }
  }
}

// ---------------------------------------------------------------------------
// Kernel 2: flash attention, S^T formulation, fixed-shift softmax,
// register-prefetch staging, swizzled LDS, PV via 16x16x16 MFMA with the
// P operand living entirely in registers (S^T C-layout == PV B-layout).
// Grid (bh fastest, 32): all q-tiles of one (b,h) -> same XCD -> L2 reuse.
// ---------------------------------------------------------------------------
__global__ __launch_bounds__(256, 2) void attn_kernel(
    const unsigned short* __restrict__ Qb,
    const unsigned short* __restrict__ QT,
    const unsigned short* __restrict__ K2b,
    const int* __restrict__ mask,
    float* __restrict__ out)
{
  __shared__ unsigned short Qa [128 * 64];  // Q  [q][d]   swizzled
  __shared__ unsigned short K2s[64 * 64];   // K2 [key][d] swizzled
  __shared__ unsigned short Vt [64 * 64];   // V^T [d][key] swizzled
#if !HAVE_MFMA16
  __shared__ unsigned short Psh[4][16][72];
#endif

  const int tid  = threadIdx.x;
  const int w    = tid >> 6;
  const int lane = tid & 63;
  const int quad = lane >> 4;
  const int l16  = lane & 15;

  const int bh = blockIdx.x;          // 0..31 (fastest -> XCD bh%8)
  const int qt = blockIdx.y;          // 0..15
  const int b = bh >> 4, h = bh & 15;
  const size_t qrow0 = (size_t)b * S_ + (size_t)qt * 128;
  const size_t krow0 = (size_t)b * S_;
  const int hc = h * 64;

  // stage Qa [q][d] from row-major Qb: pure b128 chunk copies
  {
    const int qr = tid >> 1, cb = (tid & 1) * 4;
    const size_t g = (qrow0 + qr) * D_ + hc;
    #pragma unroll
    for (int i = 0; i < 4; i++)
      *(uint4*)&Qa[swz(qr, (cb + i) * 8)] = *(const uint4*)&Qb[g + (cb + i) * 8];
  }
  __syncthreads();

  bf16x8 qfrag[2][2];
  #pragma unroll
  for (int st = 0; st < 2; st++)
    #pragma unroll
    for (int kk = 0; kk < 2; kk++)
      qfrag[st][kk] = *(const bf16x8*)&Qa[swz(w * 32 + st * 16 + l16, kk * 32 + quad * 8)];

  // c2 = -(1/8)*log2(e)*msk ; fixed shift of 12 in exp2 domain (exact by
  // softmax shift-invariance; scores bounded so no overflow)
  float c2[2], rl[2] = {0.f, 0.f};
  #pragma unroll
  for (int st = 0; st < 2; st++)
    c2[st] = (mask[qrow0 + w * 32 + st * 16 + l16] != 0) ? -0.18033688f : 0.f;

  f32x4 Ot[2][4];
  #pragma unroll
  for (int st = 0; st < 2; st++)
    #pragma unroll
    for (int dt = 0; dt < 4; dt++) Ot[st][dt] = (f32x4){0.f, 0.f, 0.f, 0.f};

  // staging coords + first prefetch
  const int rr = tid >> 2, cb0 = (tid & 3) * 2;
  const size_t kbase = (krow0 + rr) * (size_t)D_ + hc;   // + kt*64*D_
  const size_t vbase = ((size_t)hc + rr) * M_ + krow0;   // + kt*64
  uint4 preK[2], preV[2];
  #pragma unroll
  for (int i = 0; i < 2; i++) {
    preK[i] = *(const uint4*)&K2b[kbase + (cb0 + i) * 8];
    preV[i] = *(const uint4*)&QT [vbase + (cb0 + i) * 8];
  }

  for (int kt = 0; kt < S_ / 64; kt++) {
    __syncthreads();   // previous tile fully consumed
    #pragma unroll
    for (int i = 0; i < 2; i++) {
      *(uint4*)&K2s[swz(rr, (cb0 + i) * 8)] = preK[i];
      *(uint4*)&Vt [swz(rr, (cb0 + i) * 8)] = preV[i];
    }
    if (kt + 1 < S_ / 64) {
      #pragma unroll
      for (int i = 0; i < 2; i++) {
        preK[i] = *(const uint4*)&K2b[kbase + (size_t)(kt + 1) * 64 * D_ + (cb0 + i) * 8];
        preV[i] = *(const uint4*)&QT [vbase + (kt + 1) * 64 + (cb0 + i) * 8];
      }
    }
    __syncthreads();   // tile visible

    bf16x8 k2f[4][2];
    #pragma unroll
    for (int nt = 0; nt < 4; nt++)
      #pragma unroll
      for (int kk = 0; kk < 2; kk++)
        k2f[nt][kk] = *(const bf16x8*)&K2s[swz(nt * 16 + l16, kk * 32 + quad * 8)];

#if HAVE_MFMA16
    // V^T A-frags for 16x16x16: m=d=l16(+dt*16), k=key=quad*4+j (+nt*16)
    bf16x4 vf[4][4];   // [dt][nt]
    #pragma unroll
    for (int dt = 0; dt < 4; dt++)
      #pragma unroll
      for (int nt = 0; nt < 4; nt++)
        vf[dt][nt] = *(const bf16x4*)&Vt[swz(dt * 16 + l16, nt * 16 + quad * 4)];

    #pragma unroll
    for (int st = 0; st < 2; st++) {
      f32x4 sc[4];
      #pragma unroll
      for (int nt = 0; nt < 4; nt++) sc[nt] = (f32x4){0.f, 0.f, 0.f, 0.f};
      #pragma unroll
      for (int kk = 0; kk < 2; kk++)
        #pragma unroll
        for (int nt = 0; nt < 4; nt++)
          sc[nt] = __builtin_amdgcn_mfma_f32_16x16x32_bf16(k2f[nt][kk], qfrag[st][kk], sc[nt], 0, 0, 0);

      // p = exp2(c2*sc - 12); this lane's 4 p's ARE the PV B-frag for key
      // block nt (n=q=l16, k=quad*4+j) — no LDS round-trip.
      #pragma unroll
      for (int nt = 0; nt < 4; nt++) {
        const float p0 = fast_exp2(fmaf(sc[nt][0], c2[st], -12.f));
        const float p1 = fast_exp2(fmaf(sc[nt][1], c2[st], -12.f));
        const float p2 = fast_exp2(fmaf(sc[nt][2], c2[st], -12.f));
        const float p3 = fast_exp2(fmaf(sc[nt][3], c2[st], -12.f));
        rl[st] += (p0 + p1) + (p2 + p3);
        union { unsigned u[2]; bf16x4 v; } pc;
        pc.u[0] = pkbf(p0, p1);
        pc.u[1] = pkbf(p2, p3);
        #pragma unroll
        for (int dt = 0; dt < 4; dt++)
          Ot[st][dt] = MFMA16(vf[dt][nt], pc.v, Ot[st][dt]);
      }
    }
#else
    bf16x8 vf8[4][2];
    #pragma unroll
    for (int dt = 0; dt < 4; dt++)
      #pragma unroll
      for (int kk = 0; kk < 2; kk++)
        vf8[dt][kk] = *(const bf16x8*)&Vt[swz(dt * 16 + l16, kk * 32 + quad * 8)];

    #pragma unroll
    for (int st = 0; st < 2; st++) {
      f32x4 sc[4];
      #pragma unroll
      for (int nt = 0; nt < 4; nt++) sc[nt] = (f32x4){0.f, 0.f, 0.f, 0.f};
      #pragma unroll
      for (int kk = 0; kk < 2; kk++)
        #pragma unroll
        for (int nt = 0; nt < 4; nt++)
          sc[nt] = __builtin_amdgcn_mfma_f32_16x16x32_bf16(k2f[nt][kk], qfrag[st][kk], sc[nt], 0, 0, 0);

      #pragma unroll
      for (int nt = 0; nt < 4; nt++) {
        const float p0 = fast_exp2(fmaf(sc[nt][0], c2[st], -12.f));
        const float p1 = fast_exp2(fmaf(sc[nt][1], c2[st], -12.f));
        const float p2 = fast_exp2(fmaf(sc[nt][2], c2[st], -12.f));
        const float p3 = fast_exp2(fmaf(sc[nt][3], c2[st], -12.f));
        rl[st] += (p0 + p1) + (p2 + p3);
        const uint2 pk = {pkbf(p0, p1), pkbf(p2, p3)};
        *(uint2*)&Psh[w][l16][nt * 16 + quad * 4] = pk;
      }
      #pragma unroll
      for (int kk = 0; kk < 2; kk++) {
        const bf16x8 pf = *(const bf16x8*)&Psh[w][l16][kk * 32 + quad * 8];
        #pragma unroll
        for (int dt = 0; dt < 4; dt++)
          Ot[st][dt] = __builtin_amdgcn_mfma_f32_16x16x32_bf16(vf8[dt][kk], pf, Ot[st][dt], 0, 0, 0);
      }
    }
#endif
  }

  // final row-sum across quads, then write O^T / l
  #pragma unroll
  for (int st = 0; st < 2; st++) {
    float li = rl[st];
    li += __shfl_xor(li, 16);
    li += __shfl_xor(li, 32);
    const float inv = 1.f / fmaxf(li, 1e-35f);
    const size_t orow = (qrow0 + w * 32 + st * 16 + l16) * D_ + hc;
    #pragma unroll
    for (int dt = 0; dt < 4; dt++) {
      const float4 o = {Ot[st][dt][0] * inv, Ot[st][dt][1] * inv,
                        Ot[st][dt][2] * inv, Ot[st][dt][3] * inv};
      *(float4*)&out[orow + dt * 16 + quad * 4] = o;
    }
  }
}

extern "C" void kernel_launch(void* const* d_in, const int* in_sizes, int n_in,
                              void* d_out, int out_size, void* d_ws, size_t ws_size,
                              hipStream_t stream) {
  const float* hs  = (const float*)d_in[0];
  const int*   msk = (const int*)d_in[1];
  const float* Wq  = (const float*)d_in[2];
  const float* bq  = (const float*)d_in[3];
  const float* Wk  = (const float*)d_in[4];
  const float* bk  = (const float*)d_in[5];
  float* out = (float*)d_out;

  unsigned short* QT  = (unsigned short*)d_ws;             // [H*64][M_]  8 MB
  unsigned short* K2b = QT  + (size_t)D_ * M_;             // [M_][D_]    8 MB
  unsigned short* WqT = K2b + (size_t)M_ * D_;             // [D_][D_]    2 MB
  unsigned short* WkT = WqT + (size_t)D_ * D_;             // [D_][D_]    2 MB
  unsigned short* Qb  = WkT + (size_t)D_ * D_;             // [M_][D_]    8 MB

  prep_w<<<dim3(D_ / 64, D_ / 64, 2), 256, 0, stream>>>(Wq, Wk, WqT, WkT);
  proj_kernel<<<dim3(M_ / 128, D_ / 64), 256, 0, stream>>>(hs, WqT, WkT, bq, bk, Qb, K2b, QT);
  attn_kernel<<<dim3(B_ * H_, S_ / 128), 256, 0, stream>>>(Qb, QT, K2b, msk, out);
}